// Round 1
// baseline (308.619 us; speedup 1.0000x reference)
//
#include <hip/hip_runtime.h>
#include <stdint.h>

#define B_   32
#define CIN  64
#define COUT 64
#define H_   128
#define W_   128
#define WP   130
#define CIH  32   // channels staged per phase

typedef __bf16 bf16x8 __attribute__((ext_vector_type(8)));
typedef float  f32x4  __attribute__((ext_vector_type(4)));

__device__ inline unsigned int f2bf(float f) {
  union { float f; unsigned u; } uf; uf.f = f;
  unsigned u = uf.u;
  unsigned r = 0x7FFFu + ((u >> 16) & 1u);
  return (u + r) >> 16;
}

// pack two floats -> one dword of 2x bf16 (compiler emits v_cvt_pk_bf16_f32)
__device__ inline unsigned int pk2(float a, float b) {
  unsigned short x = __builtin_bit_cast(unsigned short, (__bf16)a);
  unsigned short y = __builtin_bit_cast(unsigned short, (__bf16)b);
  return (unsigned int)x | ((unsigned int)y << 16);
}

// Wb[b][p][cout][cin] = bf16(W0 + cov[b]*W1), p = kh*3+kw
__global__ __launch_bounds__(256) void prep_w(const float* __restrict__ W0,
                                              const float* __restrict__ W1,
                                              const float* __restrict__ cov,
                                              unsigned short* __restrict__ Wb) {
  int g  = blockIdx.x * 256 + threadIdx.x;   // [0, 32*9*64*64)
  int ci = g & 63;
  int co = (g >> 6) & 63;
  int v  = g >> 12;                          // b*9 + p
  int b  = v / 9;
  int p  = v - b * 9;
  int widx = (co * CIN + ci) * 9 + p;
  float val = W0[widx] + cov[b] * W1[widx];
  Wb[g] = (unsigned short)f2bf(val);
}

// stage one input row (32 channels ci0..ci0+31) into LDS row dst_row.
// Layout per pixel w': 32 bf16 channels, stored as 4 octets of 8; octet o
// lands in slot (o ^ ((w'>>1)&3)) -- XOR swizzle keeps ds_read_b128 at the
// bank floor while b64 writes stay ~2x floor.
__device__ inline void stage_phase(const float* __restrict__ X,
                                   unsigned short* dst_row,
                                   int b, int ih, int ci0, int l, int w0,
                                   bool first) {
  if (first) {
    // halo columns w'=0 and w'=129: 32 shorts = 16 dwords each
    unsigned int* d32 = (unsigned int*)dst_row;
    if (l < 16) d32[l] = 0u;                         // w'=0
    else if (l < 32) d32[129 * 16 + (l - 16)] = 0u;  // w'=129
  }
  if (ih < 0 || ih > 127) {
    if (first) {
      // zero interior w'=1..128: 8192 B = 512 int4, 8 per lane
      int4 z = {0, 0, 0, 0};
      int4* d = (int4*)(dst_row + CIH);
      #pragma unroll
      for (int k = 0; k < 8; k++) d[k * 64 + l] = z;
    }
    return;
  }
  const float* src = X + (((size_t)b * CIN + ci0) * H_ + ih) * W_ + w0;
  const int hw = H_ * W_;
  int wp0 = w0 + 1, wp1 = w0 + 2;            // this lane's two pixel slots
  int sw0 = (wp0 >> 1) & 3, sw1 = (wp1 >> 1) & 3;
  unsigned short* base0 = dst_row + wp0 * CIH;
  unsigned short* base1 = dst_row + wp1 * CIH;
  #pragma unroll 2
  for (int g = 0; g < CIH; g += 4) {
    const float* s = src + (size_t)g * hw;
    float2 a0 = *(const float2*)(s);
    float2 a1 = *(const float2*)(s + hw);
    float2 a2 = *(const float2*)(s + 2 * hw);
    float2 a3 = *(const float2*)(s + 3 * hw);
    uint2 v0, v1;
    v0.x = pk2(a0.x, a1.x); v0.y = pk2(a2.x, a3.x);   // pixel w0:   ci g..g+3
    v1.x = pk2(a0.y, a1.y); v1.y = pk2(a2.y, a3.y);   // pixel w0+1: ci g..g+3
    int o = g >> 3, pos = g & 7;
    *(uint2*)(base0 + ((o ^ sw0) << 3) + pos) = v0;
    *(uint2*)(base1 + ((o ^ sw1) << 3) + pos) = v1;
  }
}

// fused implicit-GEMM conv, K split into two 32-ci phases so LDS halves
// (33,280 B) and 4 blocks/CU fit -> 4 waves/SIMD.
__global__ __launch_bounds__(256, 4) void conv_fused(
    const float* __restrict__ X,
    const unsigned short* __restrict__ Wb,
    float* __restrict__ out) {
  __shared__ __align__(16) unsigned short Xs[4 * WP * CIH];  // 33,280 B

  int tile = blockIdx.x;          // b*64 + th
  int b  = tile >> 6;
  int h0 = (tile & 63) * 2;
  int t  = threadIdx.x;
  int wv = t >> 6;                // wave 0..3 -> staging row r
  int l  = t & 63;

  unsigned short* dst_row = Xs + wv * (WP * CIH);
  int ih = h0 - 1 + wv;
  int w0 = l << 1;

  int lh = l & 15;
  int q  = l >> 4;
  int rbase[4], cbase[4];
  #pragma unroll
  for (int nt = 0; nt < 4; nt++) {
    int p = wv * 64 + nt * 16 + lh;   // pixel in the 2x128 tile
    rbase[nt] = p >> 7;
    cbase[nt] = p & 127;
  }

  const unsigned short* wbase = Wb + (size_t)b * 9 * 64 * 64;

  f32x4 acc[4][4];

  // ---- phase 0: stage ci 0..31 ----
  stage_phase(X, dst_row, b, ih, 0, l, w0, true);
  __syncthreads();

  #pragma unroll
  for (int i = 0; i < 4; i++)
    #pragma unroll
    for (int j = 0; j < 4; j++) acc[i][j] = (f32x4){0.f, 0.f, 0.f, 0.f};

  #pragma unroll 1
  for (int ph = 0; ph < 2; ph++) {
    for (int kh = 0; kh < 3; kh++) {
      #pragma unroll
      for (int kw = 0; kw < 3; kw++) {
        const unsigned short* wk = wbase + (kh * 3 + kw) * 4096 + ph * 32;
        bf16x8 af[4], bfr[4];
        #pragma unroll
        for (int mt = 0; mt < 4; mt++)
          af[mt] = *(const bf16x8*)(wk + (mt * 16 + lh) * 64 + q * 8);
        #pragma unroll
        for (int nt = 0; nt < 4; nt++) {
          int r = rbase[nt] + kh;
          int c = cbase[nt] + kw;
          int slot = q ^ ((c >> 1) & 3);     // undo XOR swizzle
          bfr[nt] = *(const bf16x8*)(Xs + (r * WP + c) * CIH + slot * 8);
        }
        __builtin_amdgcn_s_setprio(1);
        #pragma unroll
        for (int mt = 0; mt < 4; mt++)
          #pragma unroll
          for (int nt = 0; nt < 4; nt++)
            acc[mt][nt] = __builtin_amdgcn_mfma_f32_16x16x32_bf16(
                af[mt], bfr[nt], acc[mt][nt], 0, 0, 0);
        __builtin_amdgcn_s_setprio(0);
      }
    }
    if (ph == 0) {
      __syncthreads();
      // ---- phase 1: stage ci 32..63 into the same buffer ----
      stage_phase(X, dst_row, b, ih, 32, l, w0, false);
      __syncthreads();
    }
  }

  // epilogue: C/D layout row=(lane>>4)*4+reg (cout), col=lane&15 (pixel)
  #pragma unroll
  for (int mt = 0; mt < 4; mt++) {
    int coutb = mt * 16 + q * 4;
    #pragma unroll
    for (int nt = 0; nt < 4; nt++) {
      int oh = h0 + rbase[nt];
      int ow = cbase[nt];
      #pragma unroll
      for (int r = 0; r < 4; r++) {
        int cout = coutb + r;
        out[(((size_t)b * COUT + cout) * H_ + oh) * W_ + ow] = acc[mt][nt][r];
      }
    }
  }
}

extern "C" void kernel_launch(void* const* d_in, const int* in_sizes, int n_in,
                              void* d_out, int out_size, void* d_ws, size_t ws_size,
                              hipStream_t stream) {
  const float* x   = (const float*)d_in[0];
  const float* cov = (const float*)d_in[1];
  const float* W0  = (const float*)d_in[2];
  const float* W1  = (const float*)d_in[3];
  float* out = (float*)d_out;

  unsigned short* Wb = (unsigned short*)d_ws;   // 32*9*64*64*2 = 4,718,592 B

  prep_w   <<<dim3(4608), dim3(256), 0, stream>>>(W0, W1, cov, Wb);
  conv_fused<<<dim3(2048), dim3(256), 0, stream>>>(x, Wb, out);
}

// Round 2
// 300.218 us; speedup vs baseline: 1.0280x; 1.0280x over previous
//
#include <hip/hip_runtime.h>
#include <stdint.h>

#define B_   32
#define CIN  64
#define COUT 64
#define H_   128
#define W_   128
#define WP   130

typedef __bf16 bf16x8 __attribute__((ext_vector_type(8)));
typedef float  f32x4  __attribute__((ext_vector_type(4)));

__device__ inline unsigned int f2bf(float f) {
  union { float f; unsigned u; } uf; uf.f = f;
  unsigned u = uf.u;
  unsigned r = 0x7FFFu + ((u >> 16) & 1u);
  return (u + r) >> 16;
}

// pack two floats -> one dword of 2x bf16 (v_cvt_pk_bf16_f32)
__device__ inline unsigned int pk2(float a, float b) {
  unsigned short x = __builtin_bit_cast(unsigned short, (__bf16)a);
  unsigned short y = __builtin_bit_cast(unsigned short, (__bf16)b);
  return (unsigned int)x | ((unsigned int)y << 16);
}

// Wb[b][p][cout][cin] = bf16(W0 + cov[b]*W1), p = kh*3+kw
__global__ __launch_bounds__(256) void prep_w(const float* __restrict__ W0,
                                              const float* __restrict__ W1,
                                              const float* __restrict__ cov,
                                              unsigned short* __restrict__ Wb) {
  int g  = blockIdx.x * 256 + threadIdx.x;   // [0, 32*9*64*64)
  int ci = g & 63;
  int co = (g >> 6) & 63;
  int v  = g >> 12;                          // b*9 + p
  int b  = v / 9;
  int p  = v - b * 9;
  int widx = (co * CIN + ci) * 9 + p;
  float val = W0[widx] + cov[b] * W1[widx];
  Wb[g] = (unsigned short)f2bf(val);
}

// 512-thread blocks, 8 waves. Tile = (batch b, 2 output rows, all 64 cout).
// Waves: wv>>2 = cout half (acc 32 regs/lane), wv&3 = pixel quarter.
// Staging: waves 2r,2r+1 fill LDS row r (ci halves). Single phase, one barrier.
// LDS row layout: [w' 0..129][ci-octet slot = (ci>>3)^(w'&7)][ci&7], bf16.
__global__ __launch_bounds__(512, 4) void conv_fused(
    const float* __restrict__ X,
    const unsigned short* __restrict__ Wb,
    float* __restrict__ out) {
  __shared__ __align__(16) unsigned short Xs[4 * WP * 64];  // 66,560 B

  int tile = blockIdx.x;          // b*64 + th
  int b  = tile >> 6;
  int h0 = (tile & 63) * 2;
  int t  = threadIdx.x;
  int wv = t >> 6;                // wave 0..7
  int l  = t & 63;

  // ---- staging: row r = wv>>1, ci half = wv&1 ----
  {
    int r    = wv >> 1;
    int half = wv & 1;
    unsigned short* dst_row = Xs + r * (WP * 64);
    // halo: half 0 zeros w'=0, half 1 zeros w'=129 (64 shorts = 32 dwords)
    unsigned int* d32 = (unsigned int*)(dst_row + half * (129 * 64));
    if (l < 32) d32[l] = 0u;

    int ih = h0 - 1 + r;
    if (ih < 0 || ih > 127) {
      // zero interior w'=1..128: 16384 B = 1024 int4, 2 waves x 64 lanes x 8
      int4 z = {0, 0, 0, 0};
      int4* d = (int4*)(dst_row + 64);
      #pragma unroll
      for (int k = 0; k < 8; k++) d[half * 512 + k * 64 + l] = z;
    } else {
      const int hw = H_ * W_;
      const float* src = X + (((size_t)b * CIN + half * 32) * H_ + ih) * W_ + (l << 1);
      int wp0 = (l << 1) + 1, wp1 = (l << 1) + 2;
      unsigned short* base0 = Xs + r * (WP * 64) + wp0 * 64;
      unsigned short* base1 = Xs + r * (WP * 64) + wp1 * 64;
      int s0 = wp0 & 7, s1 = wp1 & 7;
      #pragma unroll 2
      for (int g = 0; g < 32; g += 4) {
        const float* s = src + (size_t)g * hw;
        float2 a0 = *(const float2*)(s);
        float2 a1 = *(const float2*)(s + hw);
        float2 a2 = *(const float2*)(s + 2 * hw);
        float2 a3 = *(const float2*)(s + 3 * hw);
        uint2 v0, v1;
        v0.x = pk2(a0.x, a1.x); v0.y = pk2(a2.x, a3.x);   // pixel wp0: ci g..g+3
        v1.x = pk2(a0.y, a1.y); v1.y = pk2(a2.y, a3.y);   // pixel wp1: ci g..g+3
        int ci = half * 32 + g;
        int o = ci >> 3, pos = ci & 7;
        *(uint2*)(base0 + (((o ^ s0) << 3) + pos)) = v0;
        *(uint2*)(base1 + (((o ^ s1) << 3) + pos)) = v1;
      }
    }
  }
  __syncthreads();

  // ---- compute: wave = (cout half wv2, pixel quarter wvp) ----
  int wvp = wv & 3;
  int wv2 = wv >> 2;
  int lh = l & 15;
  int q  = l >> 4;

  int rbase[4], cbase[4];
  #pragma unroll
  for (int nt = 0; nt < 4; nt++) {
    int p = wvp * 64 + nt * 16 + lh;   // pixel in the 2x128 tile
    rbase[nt] = p >> 7;
    cbase[nt] = p & 127;
  }

  f32x4 acc[2][4];
  #pragma unroll
  for (int i = 0; i < 2; i++)
    #pragma unroll
    for (int j = 0; j < 4; j++) acc[i][j] = (f32x4){0.f, 0.f, 0.f, 0.f};

  // fold the cout-half offset into the weight base
  const unsigned short* wbase = Wb + (size_t)b * 9 * 4096 + (size_t)(wv2 * 32) * 64;

  #pragma unroll 1
  for (int kh = 0; kh < 3; kh++) {
    #pragma unroll 1
    for (int kw = 0; kw < 3; kw++) {
      const unsigned short* wk = wbase + (kh * 3 + kw) * 4096;
      #pragma unroll 1
      for (int ck = 0; ck < 2; ck++) {
        bf16x8 af[2], bfr[4];
        #pragma unroll
        for (int mt = 0; mt < 2; mt++)
          af[mt] = *(const bf16x8*)(wk + (mt * 16 + lh) * 64 + ck * 32 + q * 8);
        #pragma unroll
        for (int nt = 0; nt < 4; nt++) {
          int r = rbase[nt] + kh;
          int c = cbase[nt] + kw;
          int blk = (ck * 4 + q) ^ (c & 7);   // undo XOR swizzle
          bfr[nt] = *(const bf16x8*)(Xs + (r * WP + c) * 64 + blk * 8);
        }
        __builtin_amdgcn_s_setprio(1);
        #pragma unroll
        for (int mt = 0; mt < 2; mt++)
          #pragma unroll
          for (int nt = 0; nt < 4; nt++)
            acc[mt][nt] = __builtin_amdgcn_mfma_f32_16x16x32_bf16(
                af[mt], bfr[nt], acc[mt][nt], 0, 0, 0);
        __builtin_amdgcn_s_setprio(0);
      }
    }
  }

  // epilogue: C/D layout row=(lane>>4)*4+reg (cout), col=lane&15 (pixel)
  #pragma unroll
  for (int mt = 0; mt < 2; mt++) {
    int coutb = wv2 * 32 + mt * 16 + q * 4;
    #pragma unroll
    for (int nt = 0; nt < 4; nt++) {
      int oh = h0 + rbase[nt];
      int ow = cbase[nt];
      #pragma unroll
      for (int r = 0; r < 4; r++) {
        int cout = coutb + r;
        out[(((size_t)b * COUT + cout) * H_ + oh) * W_ + ow] = acc[mt][nt][r];
      }
    }
  }
}

extern "C" void kernel_launch(void* const* d_in, const int* in_sizes, int n_in,
                              void* d_out, int out_size, void* d_ws, size_t ws_size,
                              hipStream_t stream) {
  const float* x   = (const float*)d_in[0];
  const float* cov = (const float*)d_in[1];
  const float* W0  = (const float*)d_in[2];
  const float* W1  = (const float*)d_in[3];
  float* out = (float*)d_out;

  unsigned short* Wb = (unsigned short*)d_ws;   // 32*9*64*64*2 = 4,718,592 B

  prep_w   <<<dim3(4608), dim3(256), 0, stream>>>(W0, W1, cov, Wb);
  conv_fused<<<dim3(2048), dim3(512), 0, stream>>>(x, Wb, out);
}